// Round 1
// baseline (187.985 us; speedup 1.0000x reference)
//
#include <hip/hip_runtime.h>
#include <hip/hip_cooperative_groups.h>

namespace cg = cooperative_groups;

// Net_3152505995417: tiny GNN forward (N=116, E=6670, HID=64, EDIM=5).
// Algebraic collapses (exact, verified absmax=0 in prior session):
//  * node_conv: out = D @ (Hv@W) + b, D[i,j] = d[eid(i,j)] off-diag (sym).
//  * edge_conv: out[e=(a,b),k] = dv[a]*(S[a,k]-Gp[e,k]) + dv[b]*(S[b,k]-Gp[e,k]) + be,
//      Gp[f] = G[f]/(max(dv[c],dv[d],0)+eps) for f=(c,d), S[i] = sum_{f∋i} Gp[f].
// R3: the 6-dispatch chain was latency-bound (~21 us/dispatch, work is ~4 MFLOP /
//     0.5 MB — all kernels below rocprof's top-5). Fuse everything into ONE
//     cooperative kernel with 5 grid.sync() barriers; phase math unchanged.

#define NN   116
#define EE   6670
#define HID  64
#define EDIM 5
#define OUTD 4
#define ENC  122
#define EPSF 1e-10f
#define NH   (NN*HID)   // 7424
#define GB   64         // grid blocks (co-resident: 64 << 256 CUs)

__device__ __forceinline__ int eid_ij(int i, int j) {
    int a = i < j ? i : j;
    int b = i < j ? j : i;
    return a*NN - ((a*(a+1)) >> 1) + (b - a - 1);   // triu k=1 row-major
}

__global__ __launch_bounds__(256) void fused(
    const float* __restrict__ enc, const float* __restrict__ ea,
    const int* __restrict__ eidx,
    const float* __restrict__ W_enc, const float* __restrict__ b_enc,
    const float* __restrict__ W1, const float* __restrict__ b1,
    const float* __restrict__ p1, const float* __restrict__ We,
    const float* __restrict__ be, const float* __restrict__ pe,
    const float* __restrict__ W2, const float* __restrict__ b2,
    const float* __restrict__ p2, const float* __restrict__ Wl,
    const float* __restrict__ bl,
    float* __restrict__ ws, float* __restrict__ out)
{
    // One LDS arena reused per phase. Max user: phase B/E = 7424+6670+256 = 14350 floats.
    __shared__ __align__(16) float smem[14352];   // 57408 B < 64 KB static limit
    cg::grid_group grid = cg::this_grid();
    const int tid = threadIdx.x;
    const int bid = blockIdx.x;
    const int w = tid >> 6, h = tid & 63;

    // Workspace carve (floats), no aliasing needed (ws is 256 MB):
    float* Y1 = ws;                  // [NH]
    float* Y2 = ws + NH;             // [NH]
    float* d1 = ws + 2*NH;           // [EE]
    float* G  = d1 + EE;             // [EE*EDIM]
    float* dv = G + EE*EDIM;         // [NN]
    float* S  = dv + NN;             // [NN*EDIM]
    float* d2 = S + NN*EDIM;         // [EE]  (offset 55564: even -> float2 ok)
    float* P  = d2 + EE;             // [HID]

    // ---------- Phase A: X = enc@W_enc+b, Y1 = X@W1 ; d1 = ea@p1 ; G = relu(ea)@We
    if (bid < 29) {
        float* sWe  = smem;            // ENC*HID = 7808
        float* sW1  = smem + 7808;     // HID*HID = 4096 (byte off 31232, 16-aligned)
        float* sEnc = smem + 11904;    // 4*ENC = 488   (byte off 47616, 16-aligned)
        float* sX   = smem + 12392;    // 4*HID = 256
        {
            const float4* g4 = (const float4*)W_enc; float4* s4 = (float4*)sWe;
            for (int u = tid; u < ENC*HID/4; u += 256) s4[u] = g4[u];
        }
        {
            const float4* g4 = (const float4*)W1; float4* s4 = (float4*)sW1;
            for (int u = tid; u < HID*HID/4; u += 256) s4[u] = g4[u];
        }
        {
            const float4* g4 = (const float4*)(enc + bid*4*ENC);  // 1952 B/block, 16-aligned
            float4* s4 = (float4*)sEnc;
            for (int u = tid; u < 4*ENC/4; u += 256) s4[u] = g4[u];
        }
        __syncthreads();
        const int i = bid*4 + w;
        float acc = b_enc[h];
        const float* er = sEnc + w*ENC;
        #pragma unroll 4
        for (int k = 0; k < ENC; ++k) acc = fmaf(er[k], sWe[k*HID + h], acc);
        sX[w*HID + h] = acc;
        __syncthreads();
        float a2 = 0.f;
        const float* xr = sX + w*HID;
        #pragma unroll 8
        for (int k = 0; k < HID; ++k) a2 = fmaf(xr[k], sW1[k*HID + h], a2);
        Y1[i*HID + h] = a2;
    } else {
        // Edge part: EE d1-elems then EE*EDIM G-elems, grid-stride over blocks 29..GB-1.
        for (int u = (bid - 29)*256 + tid; u < EE + EE*EDIM; u += (GB - 29)*256) {
            if (u < EE) {
                const float* r = ea + u*EDIM;
                float a0 = 0.f;
                #pragma unroll
                for (int k = 0; k < EDIM; ++k) a0 = fmaf(r[k], p1[k], a0);
                d1[u] = a0;
            } else {
                int idx = u - EE;
                int e = idx / EDIM, k = idx - e*EDIM;
                const float* r = ea + e*EDIM;
                float a0 = 0.f;
                #pragma unroll
                for (int m = 0; m < EDIM; ++m) a0 = fmaf(fmaxf(r[m], 0.f), We[m*EDIM + k], a0);
                G[idx] = a0;
            }
        }
    }
    grid.sync();

    // ---------- Phase B: x2 = relu(D1@Y1+b1); dv = x2@pe^T; Y2 = x2@W2
    if (bid < 29) {
        float* sY  = smem;            // NH
        float* sD  = smem + NH;       // EE (byte off 29696, 16-aligned)
        float* sX2 = smem + 14094;    // 256
        {
            const float4* g4 = (const float4*)Y1; float4* s4 = (float4*)sY;
            for (int u = tid; u < NH/4; u += 256) s4[u] = g4[u];
            const float2* g2 = (const float2*)d1; float2* s2 = (float2*)sD;
            for (int u = tid; u < EE/2; u += 256) s2[u] = g2[u];
        }
        __syncthreads();
        const int i = bid*4 + w;
        float acc = b1[h];
        #pragma unroll 4
        for (int j = 0; j < NN; ++j) {
            int jj = (j == i) ? (j ^ 1) : j;
            float wgt = (j == i) ? 0.f : sD[eid_ij(i, jj)];
            acc = fmaf(wgt, sY[jj*HID + h], acc);
        }
        float v = fmaxf(acc, 0.f);
        float r = v * pe[h];
        #pragma unroll
        for (int off = 32; off > 0; off >>= 1) r += __shfl_down(r, off, 64);
        if (h == 0) dv[i] = r;
        sX2[w*HID + h] = v;
        __syncthreads();
        float a2 = 0.f;
        const float* xr = sX2 + w*HID;
        #pragma unroll 8
        for (int k = 0; k < HID; ++k) a2 = fmaf(xr[k], W2[k*HID + h], a2);
        Y2[i*HID + h] = a2;
    }
    grid.sync();

    // ---------- Phase C: S[i,k] = sum_{j!=i} G[eid(i,j),k] / (max(dv_i,dv_j,0)+eps)
    // one wave per (i,k): 580 wave-units, grid-stride over GB*4 = 256 waves.
    for (int wg = bid*4 + w; wg < NN*EDIM; wg += GB*4) {
        const int i = wg / EDIM, k = wg - i*EDIM;
        const float di = dv[i];
        float acc = 0.f;
        #pragma unroll
        for (int rep = 0; rep < 2; ++rep) {
            int j = h + rep*64;
            if (j < NN && j != i) {
                float cm = fmaxf(fmaxf(di, dv[j]), 0.f) + EPSF;
                acc += G[eid_ij(i, j)*EDIM + k] / cm;
            }
        }
        #pragma unroll
        for (int off = 32; off > 0; off >>= 1) acc += __shfl_down(acc, off, 64);
        if (h == 0) S[wg] = acc;
    }
    grid.sync();

    // ---------- Phase D: d2[e] = relu(edge_conv row) . p2 ; zero P
    if (bid == 0 && tid < HID) P[tid] = 0.f;
    for (int t = bid*256 + tid; t < EE; t += GB*256) {
        const int a = eidx[t], b = eidx[EE + t];
        const float da = dv[a], db = dv[b];
        const float rc = 1.f / (fmaxf(fmaxf(da, db), 0.f) + EPSF);
        float acc = 0.f;
        #pragma unroll
        for (int kk = 0; kk < EDIM; ++kk) {
            float gp = G[t*EDIM + kk] * rc;
            float v = fmaf(da, S[a*EDIM + kk] - gp, fmaf(db, S[b*EDIM + kk] - gp, be[kk]));
            acc = fmaf(fmaxf(v, 0.f), p2[kk], acc);
        }
        d2[t] = acc;
    }
    grid.sync();

    // ---------- Phase E: x3 = D2@Y2 + b2 ; block-partial pool -> atomicAdd P
    if (bid < 29) {
        float* sY = smem;
        float* sD = smem + NH;
        float* sR = smem + 14094;
        {
            const float4* g4 = (const float4*)Y2; float4* s4 = (float4*)sY;
            for (int u = tid; u < NH/4; u += 256) s4[u] = g4[u];
            const float2* g2 = (const float2*)d2; float2* s2 = (float2*)sD;
            for (int u = tid; u < EE/2; u += 256) s2[u] = g2[u];
        }
        __syncthreads();
        const int i = bid*4 + w;
        float acc = b2[h];
        #pragma unroll 4
        for (int j = 0; j < NN; ++j) {
            int jj = (j == i) ? (j ^ 1) : j;
            float wgt = (j == i) ? 0.f : sD[eid_ij(i, jj)];
            acc = fmaf(wgt, sY[jj*HID + h], acc);
        }
        sR[w*HID + h] = acc;
        __syncthreads();
        if (w == 0) {
            float s4 = sR[h] + sR[HID + h] + sR[2*HID + h] + sR[3*HID + h];
            atomicAdd(&P[h], s4);
        }
    }
    grid.sync();

    // ---------- Phase F: out = (P/N) @ Wl + bl (one wave of block 0)
    if (bid == 0 && tid < 64) {
        float val = P[tid] * (1.0f / NN);
        float res[OUTD];
        #pragma unroll
        for (int o = 0; o < OUTD; ++o) {
            float r = val * Wl[tid*OUTD + o];
            #pragma unroll
            for (int off = 32; off > 0; off >>= 1) r += __shfl_xor(r, off, 64);
            res[o] = r;
        }
        if (tid < OUTD) out[tid] = res[tid] + bl[tid];
    }
}

extern "C" void kernel_launch(void* const* d_in, const int* in_sizes, int n_in,
                              void* d_out, int out_size, void* d_ws, size_t ws_size,
                              hipStream_t stream)
{
    const float* enc   = (const float*)d_in[0];
    const float* ea    = (const float*)d_in[1];
    const int*   eidx  = (const int*)  d_in[2];
    const float* W_enc = (const float*)d_in[3];
    const float* b_enc = (const float*)d_in[4];
    const float* W1    = (const float*)d_in[5];
    const float* b1    = (const float*)d_in[6];
    const float* p1    = (const float*)d_in[7];
    const float* We    = (const float*)d_in[8];
    const float* be    = (const float*)d_in[9];
    const float* pe    = (const float*)d_in[10];
    const float* W2    = (const float*)d_in[11];
    const float* b2    = (const float*)d_in[12];
    const float* p2    = (const float*)d_in[13];
    const float* Wl    = (const float*)d_in[14];
    const float* bl    = (const float*)d_in[15];
    float* ws  = (float*)d_ws;
    float* out = (float*)d_out;

    void* args[] = {
        (void*)&enc, (void*)&ea, (void*)&eidx, (void*)&W_enc, (void*)&b_enc,
        (void*)&W1, (void*)&b1, (void*)&p1, (void*)&We, (void*)&be, (void*)&pe,
        (void*)&W2, (void*)&b2, (void*)&p2, (void*)&Wl, (void*)&bl,
        (void*)&ws, (void*)&out
    };
    hipLaunchCooperativeKernel((void*)fused, dim3(GB), dim3(256), args, 0, stream);
}